// Round 6
// baseline (1640.748 us; speedup 1.0000x reference)
//
#include <hip/hip_runtime.h>
#include <math.h>

#define DIN 128
#define HID 16
#define DOUT 12
#define NMID 11

#define CPB 128        // cols per bucket (col >> 7)
#define NBMAX 800      // max coarse buckets (runtime 782)
#define EPB 4096       // edges per binning block
#define CAP 5120       // max edges per bucket in s4 LDS (mean 4092, sigma ~64)

typedef unsigned long long ull;

// exclusive scan in place over arr[0..L), 256 threads, L <= 1024
__device__ __forceinline__ void scan4(int* arr, int L, int tid, int* wtot) {
    int lane = tid & 63, wid = tid >> 6;
    int v[4]; int s = 0;
#pragma unroll
    for (int j = 0; j < 4; ++j) {
        int idx = tid * 4 + j;
        int t = (idx < L) ? arr[idx] : 0;
        v[j] = s; s += t;
    }
    int x = s;
    for (int off = 1; off < 64; off <<= 1) {
        int y = __shfl_up(x, off, 64);
        if (lane >= off) x += y;
    }
    if (lane == 63) wtot[wid] = x;
    __syncthreads();
    if (tid == 0) { int c = 0; for (int i = 0; i < 4; ++i) { int t = wtot[i]; wtot[i] = c; c += t; } }
    __syncthreads();
    int b0 = wtot[wid] + (x - s);
#pragma unroll
    for (int j = 0; j < 4; ++j) {
        int idx = tid * 4 + j;
        if (idx < L) arr[idx] = b0 + v[j];
    }
    __syncthreads();
}

// S1: per-block coarse histogram + global bucket totals (int atomics, exact).
__global__ __launch_bounds__(256)
void s1_hist(const int* __restrict__ col, int* __restrict__ H, int* __restrict__ T,
             int E, int N, int NB) {
    __shared__ int hist[NBMAX];
    int tid = threadIdx.x;
    for (int i = tid; i < NB; i += 256) hist[i] = 0;
    __syncthreads();
    long base = (long)blockIdx.x * EPB;
    for (int r = 0; r < EPB / 256; ++r) {
        long e = base + r * 256 + tid;
        if (e < E) {
            int c = col[e];
            if ((unsigned)c < (unsigned)N) atomicAdd(&hist[c >> 7], 1);
        }
    }
    __syncthreads();
    for (int i = tid; i < NB; i += 256) {
        int h = hist[i];
        H[(long)blockIdx.x * NB + i] = h;
        if (h) atomicAdd(&T[i], h);
    }
}

// S2b: exclusive scan of bucket totals -> bStart[0..NB], single block.
__global__ __launch_bounds__(1024)
void s2b_scan(const int* __restrict__ T, int* __restrict__ bStart, int NB) {
    __shared__ int wtot[16];
    int tid = threadIdx.x, lane = tid & 63, wid = tid >> 6;
    int v = (tid < NB) ? T[tid] : 0;
    int x = v;
    for (int off = 1; off < 64; off <<= 1) {
        int y = __shfl_up(x, off, 64);
        if (lane >= off) x += y;
    }
    if (lane == 63) wtot[wid] = x;
    __syncthreads();
    if (tid == 0) { int c = 0; for (int i = 0; i < 16; ++i) { int t = wtot[i]; wtot[i] = c; c += t; } }
    __syncthreads();
    int excl = wtot[wid] + x - v;
    if (tid < NB) {
        bStart[tid] = excl;
        if (tid == NB - 1) bStart[NB] = excl + v;
    }
}

// S2c: per-(block,bucket) reservation offsets. One wave per bucket.
__global__ __launch_bounds__(256)
void s2c_scan(const int* __restrict__ H, const int* __restrict__ bStart,
              int* __restrict__ O, int NB, int nblk) {
    int wv = (blockIdx.x * 256 + threadIdx.x) >> 6;   // wave id == bucket
    int lane = threadIdx.x & 63;
    if (wv >= NB) return;
    int run = bStart[wv];
    for (int k0 = 0; k0 < nblk; k0 += 64) {
        int k = k0 + lane;
        int h = (k < nblk) ? H[(long)k * NB + wv] : 0;
        int x = h;
        for (int off = 1; off < 64; off <<= 1) {
            int y = __shfl_up(x, off, 64);
            if (lane >= off) x += y;
        }
        if (k < nblk) O[(long)k * NB + wv] = run + (x - h);
        run += __shfl(x, 63, 64);   // chunk total
    }
}

// S3: stable bin by coarse bucket. Place into LDS (bucket-contiguous, stable
// edge-id order), then flush packed int2(row|colL<<17, w) coalesced.
__global__ __launch_bounds__(256)
void s3_bin(const int* __restrict__ row, const int* __restrict__ col,
            const float* __restrict__ ew, const int* __restrict__ O,
            int2* __restrict__ bins, int E, int N, int NB) {
    __shared__ int cnt[NBMAX];
    __shared__ int dlt[NBMAX];
    __shared__ int2 ldata[EPB];
    __shared__ int gdst[EPB];
    __shared__ int wtot[4];
    int tid = threadIdx.x;
    int lane = tid & 63, wid = tid >> 6;
    long base = (long)blockIdx.x * EPB;
    for (int i = tid; i < NB; i += 256) cnt[i] = 0;
    __syncthreads();
    for (int r = 0; r < EPB / 256; ++r) {
        long e = base + r * 256 + tid;
        if (e < E) {
            int c = col[e];
            if ((unsigned)c < (unsigned)N) atomicAdd(&cnt[c >> 7], 1);
        }
    }
    __syncthreads();
    scan4(cnt, NB, tid, wtot);   // cnt = local exclusive offsets (then cursor)
    for (int i = tid; i < NB; i += 256)
        dlt[i] = O[(long)blockIdx.x * NB + i] - cnt[i];   // gpos = lpos + dlt[b]
    __syncthreads();
    ull ltm = (lane == 0) ? 0ULL : ((~0ULL) >> (64 - lane));
    for (int r = 0; r < EPB / 256; ++r) {
        long e = base + r * 256 + tid;
        bool valid = (e < E);
        int c = 0;
        if (valid) { c = col[e]; valid = ((unsigned)c < (unsigned)N); }
        int b = valid ? (c >> 7) : 0;
        int rw = 0; float wv = 0.f;
        if (valid) { rw = row[e]; wv = ew[e]; }
        ull vm = __ballot(valid);
        ull peers = vm;
        for (int bit = 0; bit < 10; ++bit) {
            ull s = __ballot(valid && ((b >> bit) & 1));
            peers &= ((b >> bit) & 1) ? s : ~s;
        }
        int rank = __popcll(peers & ltm);
        int cng  = __popcll(peers);
        int ldr  = __ffsll(peers) - 1;
        if (ldr < 0) ldr = 0;
        int lb = 0;
        for (int w = 0; w < 4; ++w) {
            if (wid == w && valid && rank == 0) lb = atomicAdd(&cnt[b], cng);
            __syncthreads();
        }
        int lbase = __shfl(lb, ldr, 64);
        if (valid) {
            int lpos = lbase + rank;
            if ((unsigned)lpos < (unsigned)EPB) {
                ldata[lpos] = make_int2(rw | ((c & (CPB - 1)) << 17), __float_as_int(wv));
                gdst[lpos]  = lpos + dlt[b];
            }
        }
    }
    __syncthreads();
    int lenBlock = (int)((E - base < (long)EPB) ? (E - base) : (long)EPB);
    for (int p = tid; p < lenBlock; p += 256) {
        int g = gdst[p];
        if ((unsigned)g < (unsigned)E) bins[g] = ldata[p];
    }
}

// S4: per bucket stable counting sort by local col into LDS, coalesced flush
// of final CSC epack(row, w), start[], then per-col in-edge-order deg sums.
__global__ __launch_bounds__(256)
void s4_sort(const int* __restrict__ bStart, int2* bins,
             int* __restrict__ start, float* __restrict__ dis,
             float* __restrict__ selfw, int E, int N) {
    __shared__ int2 ldata[CAP];
    __shared__ int hist[CPB];
    __shared__ int colStart[CPB + 1];
    __shared__ int cursor[CPB];
    __shared__ int wtot[4];
    int b = blockIdx.x;
    int tid = threadIdx.x;
    int lane = tid & 63, wid = tid >> 6;
    int segs = bStart[b], sege = bStart[b + 1];
    int len = sege - segs;
    if (len > CAP) len = CAP;          // impossible-case guard
    if (tid < CPB) hist[tid] = 0;
    __syncthreads();
    for (int p = tid; p < len; p += 256)
        atomicAdd(&hist[(bins[segs + p].x >> 17) & (CPB - 1)], 1);
    __syncthreads();
    if (tid < CPB) colStart[tid] = hist[tid];
    __syncthreads();
    scan4(colStart, CPB, tid, wtot);
    if (tid == 0) colStart[CPB] = len;
    if (tid < CPB) {
        int cg = b * CPB + tid;
        if (cg < N) start[cg] = segs + colStart[tid];
        cursor[tid] = colStart[tid];
    }
    if (b == (int)gridDim.x - 1 && tid == 0) start[N] = sege;
    __syncthreads();
    int rounds = (len + 255) / 256;
    ull ltm = (lane == 0) ? 0ULL : ((~0ULL) >> (64 - lane));
    for (int r = 0; r < rounds; ++r) {
        int p = r * 256 + tid;
        bool valid = (p < len);
        int2 d = valid ? bins[segs + p] : make_int2(0, 0);
        int c = valid ? ((d.x >> 17) & (CPB - 1)) : 0;
        ull vm = __ballot(valid);
        ull peers = vm;
        for (int bit = 0; bit < 7; ++bit) {
            ull s = __ballot(valid && ((c >> bit) & 1));
            peers &= ((c >> bit) & 1) ? s : ~s;
        }
        int rank = __popcll(peers & ltm);
        int cng  = __popcll(peers);
        int ldr  = __ffsll(peers) - 1;
        if (ldr < 0) ldr = 0;
        int lb = 0;
        for (int w = 0; w < 4; ++w) {
            if (wid == w && valid && rank == 0) lb = atomicAdd(&cursor[c], cng);
            __syncthreads();
        }
        int lbase = __shfl(lb, ldr, 64);
        if (valid) {
            int lpos = lbase + rank;
            if ((unsigned)lpos < (unsigned)CAP) ldata[lpos] = d;
        }
    }
    __syncthreads();
    for (int p = tid; p < len; p += 256) {
        int2 d = ldata[p];
        bins[segs + p] = make_int2(d.x & 0x1FFFF, d.y);
    }
    if (tid < CPB) {
        int cg = b * CPB + tid;
        if (cg < N) {
            int s0 = colStart[tid], e0 = colStart[tid + 1];
            float dsum = 0.f;
            for (int q = s0; q < e0; ++q)
                dsum = __fadd_rn(dsum, __int_as_float(ldata[q].y));
            dsum = __fadd_rn(dsum, 1.0f);
            dis[cg] = 1.0f / __fsqrt_rn(dsum);   // == 1/np.sqrt
            selfw[cg] = 1.0f / dsum;
        }
    }
}

// ---------------------------------------------------------------------------
// Degree-sorted node permutation: waves process ~equal-degree nodes so the
// agg gather loop has no divergence waste. Permutation only remaps node->
// thread; per-node FP chains are untouched (bit-identical output).
// ---------------------------------------------------------------------------

__global__ void p1_hist(const int* __restrict__ start, int* __restrict__ hist, int N) {
    int i = blockIdx.x * 256 + threadIdx.x;
    if (i < N) {
        int d = start[i + 1] - start[i];
        int b = d > 255 ? 255 : d;
        atomicAdd(&hist[255 - b], 1);    // descending degree
    }
}

__global__ __launch_bounds__(256)
void p2_scan(int* __restrict__ hist, int* __restrict__ cursor) {
    __shared__ int arr[256];
    __shared__ int wtot[4];
    int tid = threadIdx.x;
    arr[tid] = hist[tid];
    __syncthreads();
    scan4(arr, 256, tid, wtot);
    cursor[tid] = arr[tid];
}

__global__ void p3_fill(const int* __restrict__ start, int* __restrict__ cursor,
                        int* __restrict__ perm, int N) {
    int i = blockIdx.x * 256 + threadIdx.x;
    if (i < N) {
        int d = start[i + 1] - start[i];
        int b = d > 255 ? 255 : d;
        int pos = atomicAdd(&cursor[255 - b], 1);
        if ((unsigned)pos < (unsigned)N) perm[pos] = i;
    }
}

__global__ void p4_pack(const int* __restrict__ perm, const int* __restrict__ start,
                        const float* __restrict__ selfw, int4* __restrict__ nodepack,
                        int N) {
    int j = blockIdx.x * 256 + threadIdx.x;
    if (j < N) {
        int node = perm[j];
        nodepack[j] = make_int4(node, start[node], start[node + 1],
                                __float_as_int(selfw[node]));
    }
}

// S7: epack.y: w -> norm = (dis[row]*w)*dis[col], left-assoc. In-place int2.
__global__ __launch_bounds__(256)
void s7_norm(const int4* __restrict__ nodepack, int2* __restrict__ epack,
             const float* __restrict__ dis, int N) {
    int j = blockIdx.x * 256 + threadIdx.x;
    if (j >= N) return;
    int4 np = nodepack[j];
    float dc = dis[np.x];
    for (int p = np.y; p < np.z; ++p) {
        int2 d = epack[p];
        float nm = __fmul_rn(__fmul_rn(dis[d.x], __int_as_float(d.y)), dc);
        epack[p] = make_int2(d.x, __float_as_int(nm));
    }
}

// ---------------------------------------------------------------------------
// Layers: 4 threads per node, float4 lanes. Per-scalar op order identical to
// the verified round-2 kernels (sequential-k fmaf; edge-order fadd/fmul).
// ---------------------------------------------------------------------------

template <int F>
__global__ __launch_bounds__(256)
void gemm4(const float* __restrict__ h, const float* __restrict__ W,
           float* __restrict__ hw, int N, int K) {
    int g = blockIdx.x * 256 + threadIdx.x;
    int i = g >> 2, jq = g & 3;
    if (i >= N) return;
    if (jq * 4 >= F) return;
    const float4* hv = (const float4*)(h + (long)i * K);
    const float4* Wv = (const float4*)W;
    float4 acc = make_float4(0.f, 0.f, 0.f, 0.f);
    for (int k4 = 0; k4 < K / 4; ++k4) {
        float4 h4 = hv[k4];
        float4 w0 = Wv[(4 * k4 + 0) * (F / 4) + jq];
        acc.x = fmaf(h4.x, w0.x, acc.x); acc.y = fmaf(h4.x, w0.y, acc.y);
        acc.z = fmaf(h4.x, w0.z, acc.z); acc.w = fmaf(h4.x, w0.w, acc.w);
        float4 w1 = Wv[(4 * k4 + 1) * (F / 4) + jq];
        acc.x = fmaf(h4.y, w1.x, acc.x); acc.y = fmaf(h4.y, w1.y, acc.y);
        acc.z = fmaf(h4.y, w1.z, acc.z); acc.w = fmaf(h4.y, w1.w, acc.w);
        float4 w2 = Wv[(4 * k4 + 2) * (F / 4) + jq];
        acc.x = fmaf(h4.z, w2.x, acc.x); acc.y = fmaf(h4.z, w2.y, acc.y);
        acc.z = fmaf(h4.z, w2.z, acc.z); acc.w = fmaf(h4.z, w2.w, acc.w);
        float4 w3 = Wv[(4 * k4 + 3) * (F / 4) + jq];
        acc.x = fmaf(h4.w, w3.x, acc.x); acc.y = fmaf(h4.w, w3.y, acc.y);
        acc.z = fmaf(h4.w, w3.z, acc.z); acc.w = fmaf(h4.w, w3.w, acc.w);
    }
    ((float4*)hw)[(long)i * (F / 4) + jq] = acc;
}

template <int F>
__global__ __launch_bounds__(256)
void agg4(const float* __restrict__ hw, const int2* __restrict__ epack,
          const int4* __restrict__ nodepack, const float* __restrict__ bias,
          float* __restrict__ out, int N) {
    int g = blockIdx.x * 256 + threadIdx.x;
    int j = g >> 2, fq = g & 3;
    if (j >= N) return;
    if (fq * 4 >= F) return;
    const float4* hwv = (const float4*)hw;
    int4 np = nodepack[j];
    int node = np.x, s = np.y, e = np.z;
    float sw = __int_as_float(np.w);
    float4 acc = make_float4(0.f, 0.f, 0.f, 0.f);
    if (s < e) {
        int2 d0 = epack[s];
        float4 g0 = hwv[d0.x * (F / 4) + fq];
        for (int p = s; p < e; ++p) {
            int2 d1 = d0; float4 g1 = g0;
            int pn = p + 1;
            if (pn < e) { d1 = epack[pn]; g1 = hwv[d1.x * (F / 4) + fq]; }
            float nm = __int_as_float(d0.y);
            acc.x = __fadd_rn(acc.x, __fmul_rn(nm, g0.x));
            acc.y = __fadd_rn(acc.y, __fmul_rn(nm, g0.y));
            acc.z = __fadd_rn(acc.z, __fmul_rn(nm, g0.z));
            acc.w = __fadd_rn(acc.w, __fmul_rn(nm, g0.w));
            d0 = d1; g0 = g1;
        }
    }
    float4 sv = hwv[node * (F / 4) + fq];
    acc.x = __fadd_rn(acc.x, __fmul_rn(sw, sv.x));
    acc.y = __fadd_rn(acc.y, __fmul_rn(sw, sv.y));
    acc.z = __fadd_rn(acc.z, __fmul_rn(sw, sv.z));
    acc.w = __fadd_rn(acc.w, __fmul_rn(sw, sv.w));
    float4 bv = ((const float4*)bias)[fq];
    acc.x = fmaxf(__fadd_rn(acc.x, bv.x), 0.f);
    acc.y = fmaxf(__fadd_rn(acc.y, bv.y), 0.f);
    acc.z = fmaxf(__fadd_rn(acc.z, bv.z), 0.f);
    acc.w = fmaxf(__fadd_rn(acc.w, bv.w), 0.f);
    ((float4*)out)[node * (F / 4) + fq] = acc;
}

// ---------------------------------------------------------------------------

extern "C" void kernel_launch(void* const* d_in, const int* in_sizes, int n_in,
                              void* d_out, int out_size, void* d_ws, size_t ws_size,
                              hipStream_t stream) {
    const float* x      = (const float*)d_in[0];
    const int*   ei     = (const int*)d_in[1];
    const float* ew     = (const float*)d_in[2];
    const float* W0     = (const float*)d_in[3];
    const float* b0     = (const float*)d_in[4];
    const float* Wmid   = (const float*)d_in[5];
    const float* bmid   = (const float*)d_in[6];
    const float* Wlast  = (const float*)d_in[7];
    const float* blast  = (const float*)d_in[8];

    const int N = in_sizes[0] / DIN;              // 100000
    const int E = in_sizes[2];                    // 3200000
    const int* row32 = ei;
    const int* col32 = ei + E;
    const int nblk = (E + EPB - 1) / EPB;         // 782
    const int NB   = (N + CPB - 1) / CPB;         // 782 (<= NBMAX)

    char* w = (char*)d_ws;
    size_t off = 0;
    auto alloc = [&](size_t bytes) -> void* {
        void* p = w + off;
        off = (off + bytes + 255) & ~(size_t)255;
        return p;
    };
    int*  T      = (int*)alloc((size_t)NB * 4);
    int*  bStart = (int*)alloc((size_t)(NB + 1) * 4);
    int*  H      = (int*)alloc((size_t)nblk * NB * 4);
    int*  O      = (int*)alloc((size_t)nblk * NB * 4);
    int*  start  = (int*)alloc((size_t)(N + 1) * 4);
    float* dis   = (float*)alloc((size_t)N * 4);
    float* selfw = (float*)alloc((size_t)N * 4);
    int*  hist256 = (int*)alloc(256 * 4);
    int*  cur256  = (int*)alloc(256 * 4);
    int*  perm    = (int*)alloc((size_t)N * 4);
    int4* nodepack = (int4*)alloc((size_t)N * 16);
    int2* bins   = (int2*)alloc((size_t)E * 8);   // s3 out; becomes epack in s4
    float* hbuf  = (float*)alloc((size_t)N * HID * 4);
    float* hwbuf = (float*)alloc((size_t)N * HID * 4);
    (void)ws_size;

    hipMemsetAsync(T, 0, (size_t)NB * 4, stream);
    hipMemsetAsync(hist256, 0, 256 * 4, stream);

    int gridN1 = (N + 255) / 256;

    s1_hist<<<nblk, 256, 0, stream>>>(col32, H, T, E, N, NB);
    s2b_scan<<<1, 1024, 0, stream>>>(T, bStart, NB);
    s2c_scan<<<(NB * 64 + 255) / 256, 256, 0, stream>>>(H, bStart, O, NB, nblk);
    s3_bin<<<nblk, 256, 0, stream>>>(row32, col32, ew, O, bins, E, N, NB);
    s4_sort<<<NB, 256, 0, stream>>>(bStart, bins, start, dis, selfw, E, N);
    p1_hist<<<gridN1, 256, 0, stream>>>(start, hist256, N);
    p2_scan<<<1, 256, 0, stream>>>(hist256, cur256);
    p3_fill<<<gridN1, 256, 0, stream>>>(start, cur256, perm, N);
    p4_pack<<<gridN1, 256, 0, stream>>>(perm, start, selfw, nodepack, N);
    s7_norm<<<gridN1, 256, 0, stream>>>(nodepack, bins, dis, N);
    int2* epack = bins;

    int gridN4 = (N * 4 + 255) / 256;

    gemm4<HID><<<gridN4, 256, 0, stream>>>(x, W0, hwbuf, N, DIN);
    agg4<HID><<<gridN4, 256, 0, stream>>>(hwbuf, epack, nodepack, b0, hbuf, N);

    for (int l = 0; l < NMID; l++) {
        gemm4<HID><<<gridN4, 256, 0, stream>>>(hbuf, Wmid + (size_t)l * HID * HID, hwbuf, N, HID);
        agg4<HID><<<gridN4, 256, 0, stream>>>(hwbuf, epack, nodepack,
                                              bmid + (size_t)l * HID, hbuf, N);
    }

    gemm4<DOUT><<<gridN4, 256, 0, stream>>>(hbuf, Wlast, hwbuf, N, HID);
    agg4<DOUT><<<gridN4, 256, 0, stream>>>(hwbuf, epack, nodepack, blast,
                                           (float*)d_out, N);
}

// Round 7
// 1302.375 us; speedup vs baseline: 1.2598x; 1.2598x over previous
//
#include <hip/hip_runtime.h>
#include <math.h>

#define DIN 128
#define HID 16
#define DOUT 12
#define NMID 11

#define CPB 128        // cols per bucket (col >> 7)
#define NBMAX 800      // max coarse buckets (runtime 782)
#define EPB 4096       // edges per binning block
#define CAP 5120       // max edges per bucket in s4 LDS (mean 4092, sigma ~64)
#define NPB 1024       // nodes per perm-build block

typedef unsigned long long ull;

// exclusive scan in place over arr[0..L), 256 threads, L <= 1024
__device__ __forceinline__ void scan4(int* arr, int L, int tid, int* wtot) {
    int lane = tid & 63, wid = tid >> 6;
    int v[4]; int s = 0;
#pragma unroll
    for (int j = 0; j < 4; ++j) {
        int idx = tid * 4 + j;
        int t = (idx < L) ? arr[idx] : 0;
        v[j] = s; s += t;
    }
    int x = s;
    for (int off = 1; off < 64; off <<= 1) {
        int y = __shfl_up(x, off, 64);
        if (lane >= off) x += y;
    }
    if (lane == 63) wtot[wid] = x;
    __syncthreads();
    if (tid == 0) { int c = 0; for (int i = 0; i < 4; ++i) { int t = wtot[i]; wtot[i] = c; c += t; } }
    __syncthreads();
    int b0 = wtot[wid] + (x - s);
#pragma unroll
    for (int j = 0; j < 4; ++j) {
        int idx = tid * 4 + j;
        if (idx < L) arr[idx] = b0 + v[j];
    }
    __syncthreads();
}

// S1: per-block coarse histogram + global bucket totals (int atomics, exact).
__global__ __launch_bounds__(256)
void s1_hist(const int* __restrict__ col, int* __restrict__ H, int* __restrict__ T,
             int E, int N, int NB) {
    __shared__ int hist[NBMAX];
    int tid = threadIdx.x;
    for (int i = tid; i < NB; i += 256) hist[i] = 0;
    __syncthreads();
    long base = (long)blockIdx.x * EPB;
    for (int r = 0; r < EPB / 256; ++r) {
        long e = base + r * 256 + tid;
        if (e < E) {
            int c = col[e];
            if ((unsigned)c < (unsigned)N) atomicAdd(&hist[c >> 7], 1);
        }
    }
    __syncthreads();
    for (int i = tid; i < NB; i += 256) {
        int h = hist[i];
        H[(long)blockIdx.x * NB + i] = h;
        if (h) atomicAdd(&T[i], h);
    }
}

// S2b: exclusive scan of bucket totals -> bStart[0..NB], single block.
__global__ __launch_bounds__(1024)
void s2b_scan(const int* __restrict__ T, int* __restrict__ bStart, int NB) {
    __shared__ int wtot[16];
    int tid = threadIdx.x, lane = tid & 63, wid = tid >> 6;
    int v = (tid < NB) ? T[tid] : 0;
    int x = v;
    for (int off = 1; off < 64; off <<= 1) {
        int y = __shfl_up(x, off, 64);
        if (lane >= off) x += y;
    }
    if (lane == 63) wtot[wid] = x;
    __syncthreads();
    if (tid == 0) { int c = 0; for (int i = 0; i < 16; ++i) { int t = wtot[i]; wtot[i] = c; c += t; } }
    __syncthreads();
    int excl = wtot[wid] + x - v;
    if (tid < NB) {
        bStart[tid] = excl;
        if (tid == NB - 1) bStart[NB] = excl + v;
    }
}

// S2c: per-(block,bucket) reservation offsets. One wave per bucket.
__global__ __launch_bounds__(256)
void s2c_scan(const int* __restrict__ H, const int* __restrict__ bStart,
              int* __restrict__ O, int NB, int nblk) {
    int wv = (blockIdx.x * 256 + threadIdx.x) >> 6;   // wave id == bucket
    int lane = threadIdx.x & 63;
    if (wv >= NB) return;
    int run = bStart[wv];
    for (int k0 = 0; k0 < nblk; k0 += 64) {
        int k = k0 + lane;
        int h = (k < nblk) ? H[(long)k * NB + wv] : 0;
        int x = h;
        for (int off = 1; off < 64; off <<= 1) {
            int y = __shfl_up(x, off, 64);
            if (lane >= off) x += y;
        }
        if (k < nblk) O[(long)k * NB + wv] = run + (x - h);
        run += __shfl(x, 63, 64);   // chunk total
    }
}

// S3: stable bin by coarse bucket. Place into LDS (bucket-contiguous, stable
// edge-id order), then flush packed int2(row|colL<<17, w) coalesced.
__global__ __launch_bounds__(256)
void s3_bin(const int* __restrict__ row, const int* __restrict__ col,
            const float* __restrict__ ew, const int* __restrict__ O,
            int2* __restrict__ bins, int E, int N, int NB) {
    __shared__ int cnt[NBMAX];
    __shared__ int dlt[NBMAX];
    __shared__ int2 ldata[EPB];
    __shared__ int gdst[EPB];
    __shared__ int wtot[4];
    int tid = threadIdx.x;
    int lane = tid & 63, wid = tid >> 6;
    long base = (long)blockIdx.x * EPB;
    for (int i = tid; i < NB; i += 256) cnt[i] = 0;
    __syncthreads();
    for (int r = 0; r < EPB / 256; ++r) {
        long e = base + r * 256 + tid;
        if (e < E) {
            int c = col[e];
            if ((unsigned)c < (unsigned)N) atomicAdd(&cnt[c >> 7], 1);
        }
    }
    __syncthreads();
    scan4(cnt, NB, tid, wtot);   // cnt = local exclusive offsets (then cursor)
    for (int i = tid; i < NB; i += 256)
        dlt[i] = O[(long)blockIdx.x * NB + i] - cnt[i];   // gpos = lpos + dlt[b]
    __syncthreads();
    ull ltm = (lane == 0) ? 0ULL : ((~0ULL) >> (64 - lane));
    for (int r = 0; r < EPB / 256; ++r) {
        long e = base + r * 256 + tid;
        bool valid = (e < E);
        int c = 0;
        if (valid) { c = col[e]; valid = ((unsigned)c < (unsigned)N); }
        int b = valid ? (c >> 7) : 0;
        int rw = 0; float wv = 0.f;
        if (valid) { rw = row[e]; wv = ew[e]; }
        ull vm = __ballot(valid);
        ull peers = vm;
        for (int bit = 0; bit < 10; ++bit) {
            ull s = __ballot(valid && ((b >> bit) & 1));
            peers &= ((b >> bit) & 1) ? s : ~s;
        }
        int rank = __popcll(peers & ltm);
        int cng  = __popcll(peers);
        int ldr  = __ffsll(peers) - 1;
        if (ldr < 0) ldr = 0;
        int lb = 0;
        for (int w = 0; w < 4; ++w) {
            if (wid == w && valid && rank == 0) lb = atomicAdd(&cnt[b], cng);
            __syncthreads();
        }
        int lbase = __shfl(lb, ldr, 64);
        if (valid) {
            int lpos = lbase + rank;
            if ((unsigned)lpos < (unsigned)EPB) {
                ldata[lpos] = make_int2(rw | ((c & (CPB - 1)) << 17), __float_as_int(wv));
                gdst[lpos]  = lpos + dlt[b];
            }
        }
    }
    __syncthreads();
    int lenBlock = (int)((E - base < (long)EPB) ? (E - base) : (long)EPB);
    for (int p = tid; p < lenBlock; p += 256) {
        int g = gdst[p];
        if ((unsigned)g < (unsigned)E) bins[g] = ldata[p];
    }
}

// S4: per bucket stable counting sort by local col into LDS, coalesced flush
// of final CSC epack(row, w), start[], then per-col in-edge-order deg sums.
__global__ __launch_bounds__(256)
void s4_sort(const int* __restrict__ bStart, int2* bins,
             int* __restrict__ start, float* __restrict__ dis,
             float* __restrict__ selfw, int E, int N) {
    __shared__ int2 ldata[CAP];
    __shared__ int hist[CPB];
    __shared__ int colStart[CPB + 1];
    __shared__ int cursor[CPB];
    __shared__ int wtot[4];
    int b = blockIdx.x;
    int tid = threadIdx.x;
    int lane = tid & 63, wid = tid >> 6;
    int segs = bStart[b], sege = bStart[b + 1];
    int len = sege - segs;
    if (len > CAP) len = CAP;          // impossible-case guard
    if (tid < CPB) hist[tid] = 0;
    __syncthreads();
    for (int p = tid; p < len; p += 256)
        atomicAdd(&hist[(bins[segs + p].x >> 17) & (CPB - 1)], 1);
    __syncthreads();
    if (tid < CPB) colStart[tid] = hist[tid];
    __syncthreads();
    scan4(colStart, CPB, tid, wtot);
    if (tid == 0) colStart[CPB] = len;
    if (tid < CPB) {
        int cg = b * CPB + tid;
        if (cg < N) start[cg] = segs + colStart[tid];
        cursor[tid] = colStart[tid];
    }
    if (b == (int)gridDim.x - 1 && tid == 0) start[N] = sege;
    __syncthreads();
    int rounds = (len + 255) / 256;
    ull ltm = (lane == 0) ? 0ULL : ((~0ULL) >> (64 - lane));
    for (int r = 0; r < rounds; ++r) {
        int p = r * 256 + tid;
        bool valid = (p < len);
        int2 d = valid ? bins[segs + p] : make_int2(0, 0);
        int c = valid ? ((d.x >> 17) & (CPB - 1)) : 0;
        ull vm = __ballot(valid);
        ull peers = vm;
        for (int bit = 0; bit < 7; ++bit) {
            ull s = __ballot(valid && ((c >> bit) & 1));
            peers &= ((c >> bit) & 1) ? s : ~s;
        }
        int rank = __popcll(peers & ltm);
        int cng  = __popcll(peers);
        int ldr  = __ffsll(peers) - 1;
        if (ldr < 0) ldr = 0;
        int lb = 0;
        for (int w = 0; w < 4; ++w) {
            if (wid == w && valid && rank == 0) lb = atomicAdd(&cursor[c], cng);
            __syncthreads();
        }
        int lbase = __shfl(lb, ldr, 64);
        if (valid) {
            int lpos = lbase + rank;
            if ((unsigned)lpos < (unsigned)CAP) ldata[lpos] = d;
        }
    }
    __syncthreads();
    for (int p = tid; p < len; p += 256) {
        int2 d = ldata[p];
        bins[segs + p] = make_int2(d.x & 0x1FFFF, d.y);
    }
    if (tid < CPB) {
        int cg = b * CPB + tid;
        if (cg < N) {
            int s0 = colStart[tid], e0 = colStart[tid + 1];
            float dsum = 0.f;
            for (int q = s0; q < e0; ++q)
                dsum = __fadd_rn(dsum, __int_as_float(ldata[q].y));
            dsum = __fadd_rn(dsum, 1.0f);
            dis[cg] = 1.0f / __fsqrt_rn(dsum);   // == 1/np.sqrt
            selfw[cg] = 1.0f / dsum;
        }
    }
}

// ---------------------------------------------------------------------------
// Degree-sorted node permutation, built with the scan machinery (NO contended
// global atomics — R6's p1/p3 global 256-bin atomics cost 350 us).
// bin = 255 - min(deg,255)  (descending degree).
// ---------------------------------------------------------------------------

__device__ __forceinline__ int deg_bin(const int* start, int i) {
    int d = start[i + 1] - start[i];
    return 255 - (d > 255 ? 255 : d);
}

// pd1: per-block LDS histogram over 256 degree bins.
__global__ __launch_bounds__(256)
void pd1_hist(const int* __restrict__ start, int* __restrict__ HD, int N) {
    __shared__ int hist[256];
    int tid = threadIdx.x;
    hist[tid] = 0;
    __syncthreads();
    int base = blockIdx.x * NPB;
    for (int r = 0; r < NPB / 256; ++r) {
        int i = base + r * 256 + tid;
        if (i < N) atomicAdd(&hist[deg_bin(start, i)], 1);
    }
    __syncthreads();
    HD[blockIdx.x * 256 + tid] = hist[tid];
}

// pd2a: bin totals -> exclusive binStart[256]. Single block.
__global__ __launch_bounds__(256)
void pd2a_scan(const int* __restrict__ HD, int* __restrict__ binStart, int nbk) {
    __shared__ int arr[256];
    __shared__ int wtot[4];
    int tid = threadIdx.x;
    int tot = 0;
    for (int k = 0; k < nbk; ++k) tot += HD[k * 256 + tid];
    arr[tid] = tot;
    __syncthreads();
    scan4(arr, 256, tid, wtot);
    binStart[tid] = arr[tid];
}

// pd2b: per-(block,bin) reservation offsets; one wave per bin.
__global__ __launch_bounds__(256)
void pd2b_off(const int* __restrict__ HD, const int* __restrict__ binStart,
              int* __restrict__ OD, int nbk) {
    int wv = (blockIdx.x * 256 + threadIdx.x) >> 6;
    int lane = threadIdx.x & 63;
    if (wv >= 256) return;
    int run = binStart[wv];
    for (int k0 = 0; k0 < nbk; k0 += 64) {
        int k = k0 + lane;
        int h = (k < nbk) ? HD[k * 256 + wv] : 0;
        int x = h;
        for (int off = 1; off < 64; off <<= 1) {
            int y = __shfl_up(x, off, 64);
            if (lane >= off) x += y;
        }
        if (k < nbk) OD[k * 256 + wv] = run + (x - h);
        run += __shfl(x, 63, 64);
    }
}

// pd3: stable placement into perm (LDS cursors + ballot ranks).
__global__ __launch_bounds__(256)
void pd3_fill(const int* __restrict__ start, const int* __restrict__ OD,
              int* __restrict__ perm, int N) {
    __shared__ int cnt[256];
    __shared__ int dlt[256];
    __shared__ int wtot[4];
    int tid = threadIdx.x;
    int lane = tid & 63, wid = tid >> 6;
    int base = blockIdx.x * NPB;
    cnt[tid] = 0;
    __syncthreads();
    for (int r = 0; r < NPB / 256; ++r) {
        int i = base + r * 256 + tid;
        if (i < N) atomicAdd(&cnt[deg_bin(start, i)], 1);
    }
    __syncthreads();
    scan4(cnt, 256, tid, wtot);
    dlt[tid] = OD[blockIdx.x * 256 + tid] - cnt[tid];
    __syncthreads();
    ull ltm = (lane == 0) ? 0ULL : ((~0ULL) >> (64 - lane));
    for (int r = 0; r < NPB / 256; ++r) {
        int i = base + r * 256 + tid;
        bool valid = (i < N);
        int b = valid ? deg_bin(start, i) : 0;
        ull peers = __ballot(valid);
        for (int bit = 0; bit < 8; ++bit) {
            ull s = __ballot(valid && ((b >> bit) & 1));
            peers &= ((b >> bit) & 1) ? s : ~s;
        }
        int rank = __popcll(peers & ltm);
        int cng  = __popcll(peers);
        int ldr  = __ffsll(peers) - 1;
        if (ldr < 0) ldr = 0;
        int lb = 0;
        for (int w = 0; w < 4; ++w) {
            if (wid == w && valid && rank == 0) lb = atomicAdd(&cnt[b], cng);
            __syncthreads();
        }
        int lbase = __shfl(lb, ldr, 64);
        if (valid) {
            int gpos = lbase + rank + dlt[b];
            if ((unsigned)gpos < (unsigned)N) perm[gpos] = i;
        }
    }
}

__global__ void pd4_inv(const int* __restrict__ perm, int* __restrict__ iperm, int N) {
    int j = blockIdx.x * 256 + threadIdx.x;
    if (j < N) {
        int node = perm[j];
        if ((unsigned)node < (unsigned)N) iperm[node] = j;
    }
}

// nodepack[j] = {node, start[node], end[node], selfw[node]}
__global__ void p4_pack(const int* __restrict__ perm, const int* __restrict__ start,
                        const float* __restrict__ selfw, int4* __restrict__ nodepack,
                        int N) {
    int j = blockIdx.x * 256 + threadIdx.x;
    if (j < N) {
        int node = perm[j];
        nodepack[j] = make_int4(node, start[node], start[node + 1],
                                __float_as_int(selfw[node]));
    }
}

// S7: epack -> {iperm[row], norm}. norm = (dis[row]*w)*dis[col], left-assoc.
__global__ __launch_bounds__(256)
void s7_norm(const int4* __restrict__ nodepack, int2* __restrict__ epack,
             const float* __restrict__ dis, const int* __restrict__ iperm, int N) {
    int j = blockIdx.x * 256 + threadIdx.x;
    if (j >= N) return;
    int4 np = nodepack[j];
    float dc = dis[np.x];
    for (int p = np.y; p < np.z; ++p) {
        int2 d = epack[p];
        float nm = __fmul_rn(__fmul_rn(dis[d.x], __int_as_float(d.y)), dc);
        epack[p] = make_int2(iperm[d.x], __float_as_int(nm));
    }
}

// ---------------------------------------------------------------------------
// Layers in PERMUTED space: hbuf/hwbuf row j holds node perm[j]. Layer-0 gemm
// gathers x rows via perm; epack.x is pre-mapped to permuted indices; agg
// self-row and output writes are linear; only the final layer scatters to
// d_out in original order. Per-scalar FP op order identical to round 2.
// ---------------------------------------------------------------------------

template <int F, bool PERMROW>
__global__ __launch_bounds__(256)
void gemm4(const float* __restrict__ h, const float* __restrict__ W,
           float* __restrict__ hw, const int* __restrict__ perm, int N, int K) {
    int g = blockIdx.x * 256 + threadIdx.x;
    int i = g >> 2, jq = g & 3;
    if (i >= N) return;
    if (jq * 4 >= F) return;
    int row = PERMROW ? perm[i] : i;
    const float4* hv = (const float4*)(h + (long)row * K);
    const float4* Wv = (const float4*)W;
    float4 acc = make_float4(0.f, 0.f, 0.f, 0.f);
    for (int k4 = 0; k4 < K / 4; ++k4) {
        float4 h4 = hv[k4];
        float4 w0 = Wv[(4 * k4 + 0) * (F / 4) + jq];
        acc.x = fmaf(h4.x, w0.x, acc.x); acc.y = fmaf(h4.x, w0.y, acc.y);
        acc.z = fmaf(h4.x, w0.z, acc.z); acc.w = fmaf(h4.x, w0.w, acc.w);
        float4 w1 = Wv[(4 * k4 + 1) * (F / 4) + jq];
        acc.x = fmaf(h4.y, w1.x, acc.x); acc.y = fmaf(h4.y, w1.y, acc.y);
        acc.z = fmaf(h4.y, w1.z, acc.z); acc.w = fmaf(h4.y, w1.w, acc.w);
        float4 w2 = Wv[(4 * k4 + 2) * (F / 4) + jq];
        acc.x = fmaf(h4.z, w2.x, acc.x); acc.y = fmaf(h4.z, w2.y, acc.y);
        acc.z = fmaf(h4.z, w2.z, acc.z); acc.w = fmaf(h4.z, w2.w, acc.w);
        float4 w3 = Wv[(4 * k4 + 3) * (F / 4) + jq];
        acc.x = fmaf(h4.w, w3.x, acc.x); acc.y = fmaf(h4.w, w3.y, acc.y);
        acc.z = fmaf(h4.w, w3.z, acc.z); acc.w = fmaf(h4.w, w3.w, acc.w);
    }
    ((float4*)hw)[(long)i * (F / 4) + jq] = acc;
}

template <int F, bool FINAL>
__global__ __launch_bounds__(256)
void agg4(const float* __restrict__ hw, const int2* __restrict__ epack,
          const int4* __restrict__ nodepack, const float* __restrict__ bias,
          float* __restrict__ out, int N) {
    int g = blockIdx.x * 256 + threadIdx.x;
    int j = g >> 2, fq = g & 3;
    if (j >= N) return;
    if (fq * 4 >= F) return;
    const float4* hwv = (const float4*)hw;
    int4 np = nodepack[j];
    int s = np.y, e = np.z;
    float sw = __int_as_float(np.w);
    float4 acc = make_float4(0.f, 0.f, 0.f, 0.f);
    if (s < e) {
        int2 d0 = epack[s];
        float4 g0 = hwv[d0.x * (F / 4) + fq];
        for (int p = s; p < e; ++p) {
            int2 d1 = d0; float4 g1 = g0;
            int pn = p + 1;
            if (pn < e) { d1 = epack[pn]; g1 = hwv[d1.x * (F / 4) + fq]; }
            float nm = __int_as_float(d0.y);
            acc.x = __fadd_rn(acc.x, __fmul_rn(nm, g0.x));
            acc.y = __fadd_rn(acc.y, __fmul_rn(nm, g0.y));
            acc.z = __fadd_rn(acc.z, __fmul_rn(nm, g0.z));
            acc.w = __fadd_rn(acc.w, __fmul_rn(nm, g0.w));
            d0 = d1; g0 = g1;
        }
    }
    float4 sv = hwv[(long)j * (F / 4) + fq];   // self row: linear in perm space
    acc.x = __fadd_rn(acc.x, __fmul_rn(sw, sv.x));
    acc.y = __fadd_rn(acc.y, __fmul_rn(sw, sv.y));
    acc.z = __fadd_rn(acc.z, __fmul_rn(sw, sv.z));
    acc.w = __fadd_rn(acc.w, __fmul_rn(sw, sv.w));
    float4 bv = ((const float4*)bias)[fq];
    acc.x = fmaxf(__fadd_rn(acc.x, bv.x), 0.f);
    acc.y = fmaxf(__fadd_rn(acc.y, bv.y), 0.f);
    acc.z = fmaxf(__fadd_rn(acc.z, bv.z), 0.f);
    acc.w = fmaxf(__fadd_rn(acc.w, bv.w), 0.f);
    long orow = FINAL ? (long)np.x : (long)j;   // final: scatter to original id
    ((float4*)out)[orow * (F / 4) + fq] = acc;
}

// ---------------------------------------------------------------------------

extern "C" void kernel_launch(void* const* d_in, const int* in_sizes, int n_in,
                              void* d_out, int out_size, void* d_ws, size_t ws_size,
                              hipStream_t stream) {
    const float* x      = (const float*)d_in[0];
    const int*   ei     = (const int*)d_in[1];
    const float* ew     = (const float*)d_in[2];
    const float* W0     = (const float*)d_in[3];
    const float* b0     = (const float*)d_in[4];
    const float* Wmid   = (const float*)d_in[5];
    const float* bmid   = (const float*)d_in[6];
    const float* Wlast  = (const float*)d_in[7];
    const float* blast  = (const float*)d_in[8];

    const int N = in_sizes[0] / DIN;              // 100000
    const int E = in_sizes[2];                    // 3200000
    const int* row32 = ei;
    const int* col32 = ei + E;
    const int nblk = (E + EPB - 1) / EPB;         // 782
    const int NB   = (N + CPB - 1) / CPB;         // 782 (<= NBMAX)
    const int nbk  = (N + NPB - 1) / NPB;         // 98

    char* w = (char*)d_ws;
    size_t off = 0;
    auto alloc = [&](size_t bytes) -> void* {
        void* p = w + off;
        off = (off + bytes + 255) & ~(size_t)255;
        return p;
    };
    int*  T      = (int*)alloc((size_t)NB * 4);
    int*  bStart = (int*)alloc((size_t)(NB + 1) * 4);
    int*  H      = (int*)alloc((size_t)nblk * NB * 4);
    int*  O      = (int*)alloc((size_t)nblk * NB * 4);
    int*  start  = (int*)alloc((size_t)(N + 1) * 4);
    float* dis   = (float*)alloc((size_t)N * 4);
    float* selfw = (float*)alloc((size_t)N * 4);
    int*  HD     = (int*)alloc((size_t)nbk * 256 * 4);
    int*  OD     = (int*)alloc((size_t)nbk * 256 * 4);
    int*  binStart = (int*)alloc(257 * 4);
    int*  perm   = (int*)alloc((size_t)N * 4);
    int*  iperm  = (int*)alloc((size_t)N * 4);
    int4* nodepack = (int4*)alloc((size_t)N * 16);
    int2* bins   = (int2*)alloc((size_t)E * 8);   // s3 out; becomes epack in s4
    float* hbuf  = (float*)alloc((size_t)N * HID * 4);
    float* hwbuf = (float*)alloc((size_t)N * HID * 4);
    (void)ws_size;

    hipMemsetAsync(T, 0, (size_t)NB * 4, stream);

    int gridN1 = (N + 255) / 256;

    s1_hist<<<nblk, 256, 0, stream>>>(col32, H, T, E, N, NB);
    s2b_scan<<<1, 1024, 0, stream>>>(T, bStart, NB);
    s2c_scan<<<(NB * 64 + 255) / 256, 256, 0, stream>>>(H, bStart, O, NB, nblk);
    s3_bin<<<nblk, 256, 0, stream>>>(row32, col32, ew, O, bins, E, N, NB);
    s4_sort<<<NB, 256, 0, stream>>>(bStart, bins, start, dis, selfw, E, N);
    pd1_hist<<<nbk, 256, 0, stream>>>(start, HD, N);
    pd2a_scan<<<1, 256, 0, stream>>>(HD, binStart, nbk);
    pd2b_off<<<64, 256, 0, stream>>>(HD, binStart, OD, nbk);
    pd3_fill<<<nbk, 256, 0, stream>>>(start, OD, perm, N);
    pd4_inv<<<gridN1, 256, 0, stream>>>(perm, iperm, N);
    p4_pack<<<gridN1, 256, 0, stream>>>(perm, start, selfw, nodepack, N);
    s7_norm<<<gridN1, 256, 0, stream>>>(nodepack, bins, dis, iperm, N);
    int2* epack = bins;

    int gridN4 = (N * 4 + 255) / 256;

    gemm4<HID, true><<<gridN4, 256, 0, stream>>>(x, W0, hwbuf, perm, N, DIN);
    agg4<HID, false><<<gridN4, 256, 0, stream>>>(hwbuf, epack, nodepack, b0, hbuf, N);

    for (int l = 0; l < NMID; l++) {
        gemm4<HID, false><<<gridN4, 256, 0, stream>>>(hbuf, Wmid + (size_t)l * HID * HID,
                                                      hwbuf, perm, N, HID);
        agg4<HID, false><<<gridN4, 256, 0, stream>>>(hwbuf, epack, nodepack,
                                                     bmid + (size_t)l * HID, hbuf, N);
    }

    gemm4<DOUT, false><<<gridN4, 256, 0, stream>>>(hbuf, Wlast, hwbuf, perm, N, HID);
    agg4<DOUT, true><<<gridN4, 256, 0, stream>>>(hwbuf, epack, nodepack, blast,
                                                 (float*)d_out, N);
}

// Round 8
// 1158.921 us; speedup vs baseline: 1.4158x; 1.1238x over previous
//
#include <hip/hip_runtime.h>
#include <math.h>

#define DIN 128
#define HID 16
#define DOUT 12
#define NMID 11

#define CPB 128        // cols per bucket (col >> 7)
#define NBMAX 800      // max coarse buckets (runtime 782)
#define EPB 4096       // edges per binning block
#define CAP 5120       // max edges per bucket in s4 LDS (mean 4092, sigma ~64)
#define NPB 1024       // nodes per perm-build block

typedef unsigned long long ull;

// exclusive scan in place over arr[0..L), 256 threads, L <= 1024
__device__ __forceinline__ void scan4(int* arr, int L, int tid, int* wtot) {
    int lane = tid & 63, wid = tid >> 6;
    int v[4]; int s = 0;
#pragma unroll
    for (int j = 0; j < 4; ++j) {
        int idx = tid * 4 + j;
        int t = (idx < L) ? arr[idx] : 0;
        v[j] = s; s += t;
    }
    int x = s;
    for (int off = 1; off < 64; off <<= 1) {
        int y = __shfl_up(x, off, 64);
        if (lane >= off) x += y;
    }
    if (lane == 63) wtot[wid] = x;
    __syncthreads();
    if (tid == 0) { int c = 0; for (int i = 0; i < 4; ++i) { int t = wtot[i]; wtot[i] = c; c += t; } }
    __syncthreads();
    int b0 = wtot[wid] + (x - s);
#pragma unroll
    for (int j = 0; j < 4; ++j) {
        int idx = tid * 4 + j;
        if (idx < L) arr[idx] = b0 + v[j];
    }
    __syncthreads();
}

// S1: per-block coarse histogram + global bucket totals (int atomics, exact).
__global__ __launch_bounds__(256)
void s1_hist(const int* __restrict__ col, int* __restrict__ H, int* __restrict__ T,
             int E, int N, int NB) {
    __shared__ int hist[NBMAX];
    int tid = threadIdx.x;
    for (int i = tid; i < NB; i += 256) hist[i] = 0;
    __syncthreads();
    long base = (long)blockIdx.x * EPB;
    for (int r = 0; r < EPB / 256; ++r) {
        long e = base + r * 256 + tid;
        if (e < E) {
            int c = col[e];
            if ((unsigned)c < (unsigned)N) atomicAdd(&hist[c >> 7], 1);
        }
    }
    __syncthreads();
    for (int i = tid; i < NB; i += 256) {
        int h = hist[i];
        H[(long)blockIdx.x * NB + i] = h;
        if (h) atomicAdd(&T[i], h);
    }
}

// S2b: exclusive scan of bucket totals -> bStart[0..NB], single block.
__global__ __launch_bounds__(1024)
void s2b_scan(const int* __restrict__ T, int* __restrict__ bStart, int NB) {
    __shared__ int wtot[16];
    int tid = threadIdx.x, lane = tid & 63, wid = tid >> 6;
    int v = (tid < NB) ? T[tid] : 0;
    int x = v;
    for (int off = 1; off < 64; off <<= 1) {
        int y = __shfl_up(x, off, 64);
        if (lane >= off) x += y;
    }
    if (lane == 63) wtot[wid] = x;
    __syncthreads();
    if (tid == 0) { int c = 0; for (int i = 0; i < 16; ++i) { int t = wtot[i]; wtot[i] = c; c += t; } }
    __syncthreads();
    int excl = wtot[wid] + x - v;
    if (tid < NB) {
        bStart[tid] = excl;
        if (tid == NB - 1) bStart[NB] = excl + v;
    }
}

// S2c: per-(block,bucket) reservation offsets. One wave per bucket.
__global__ __launch_bounds__(256)
void s2c_scan(const int* __restrict__ H, const int* __restrict__ bStart,
              int* __restrict__ O, int NB, int nblk) {
    int wv = (blockIdx.x * 256 + threadIdx.x) >> 6;   // wave id == bucket
    int lane = threadIdx.x & 63;
    if (wv >= NB) return;
    int run = bStart[wv];
    for (int k0 = 0; k0 < nblk; k0 += 64) {
        int k = k0 + lane;
        int h = (k < nblk) ? H[(long)k * NB + wv] : 0;
        int x = h;
        for (int off = 1; off < 64; off <<= 1) {
            int y = __shfl_up(x, off, 64);
            if (lane >= off) x += y;
        }
        if (k < nblk) O[(long)k * NB + wv] = run + (x - h);
        run += __shfl(x, 63, 64);   // chunk total
    }
}

// S3: stable bin by coarse bucket. Place into LDS (bucket-contiguous, stable
// edge-id order), then flush packed int2(row|colL<<17, w) coalesced.
__global__ __launch_bounds__(256)
void s3_bin(const int* __restrict__ row, const int* __restrict__ col,
            const float* __restrict__ ew, const int* __restrict__ O,
            int2* __restrict__ bins, int E, int N, int NB) {
    __shared__ int cnt[NBMAX];
    __shared__ int dlt[NBMAX];
    __shared__ int2 ldata[EPB];
    __shared__ int gdst[EPB];
    __shared__ int wtot[4];
    int tid = threadIdx.x;
    int lane = tid & 63, wid = tid >> 6;
    long base = (long)blockIdx.x * EPB;
    for (int i = tid; i < NB; i += 256) cnt[i] = 0;
    __syncthreads();
    for (int r = 0; r < EPB / 256; ++r) {
        long e = base + r * 256 + tid;
        if (e < E) {
            int c = col[e];
            if ((unsigned)c < (unsigned)N) atomicAdd(&cnt[c >> 7], 1);
        }
    }
    __syncthreads();
    scan4(cnt, NB, tid, wtot);   // cnt = local exclusive offsets (then cursor)
    for (int i = tid; i < NB; i += 256)
        dlt[i] = O[(long)blockIdx.x * NB + i] - cnt[i];   // gpos = lpos + dlt[b]
    __syncthreads();
    ull ltm = (lane == 0) ? 0ULL : ((~0ULL) >> (64 - lane));
    for (int r = 0; r < EPB / 256; ++r) {
        long e = base + r * 256 + tid;
        bool valid = (e < E);
        int c = 0;
        if (valid) { c = col[e]; valid = ((unsigned)c < (unsigned)N); }
        int b = valid ? (c >> 7) : 0;
        int rw = 0; float wv = 0.f;
        if (valid) { rw = row[e]; wv = ew[e]; }
        ull vm = __ballot(valid);
        ull peers = vm;
        for (int bit = 0; bit < 10; ++bit) {
            ull s = __ballot(valid && ((b >> bit) & 1));
            peers &= ((b >> bit) & 1) ? s : ~s;
        }
        int rank = __popcll(peers & ltm);
        int cng  = __popcll(peers);
        int ldr  = __ffsll(peers) - 1;
        if (ldr < 0) ldr = 0;
        int lb = 0;
        for (int w = 0; w < 4; ++w) {
            if (wid == w && valid && rank == 0) lb = atomicAdd(&cnt[b], cng);
            __syncthreads();
        }
        int lbase = __shfl(lb, ldr, 64);
        if (valid) {
            int lpos = lbase + rank;
            if ((unsigned)lpos < (unsigned)EPB) {
                ldata[lpos] = make_int2(rw | ((c & (CPB - 1)) << 17), __float_as_int(wv));
                gdst[lpos]  = lpos + dlt[b];
            }
        }
    }
    __syncthreads();
    int lenBlock = (int)((E - base < (long)EPB) ? (E - base) : (long)EPB);
    for (int p = tid; p < lenBlock; p += 256) {
        int g = gdst[p];
        if ((unsigned)g < (unsigned)E) bins[g] = ldata[p];
    }
}

// S4: per bucket stable counting sort by local col into LDS, coalesced flush
// (keeps colL bits for the edge-parallel s7), start[], per-col deg sums.
__global__ __launch_bounds__(256)
void s4_sort(const int* __restrict__ bStart, int2* bins,
             int* __restrict__ start, float* __restrict__ dis,
             float* __restrict__ selfw, int E, int N) {
    __shared__ int2 ldata[CAP];
    __shared__ int hist[CPB];
    __shared__ int colStart[CPB + 1];
    __shared__ int cursor[CPB];
    __shared__ int wtot[4];
    int b = blockIdx.x;
    int tid = threadIdx.x;
    int lane = tid & 63, wid = tid >> 6;
    int segs = bStart[b], sege = bStart[b + 1];
    int len = sege - segs;
    if (len > CAP) len = CAP;          // impossible-case guard
    if (tid < CPB) hist[tid] = 0;
    __syncthreads();
    for (int p = tid; p < len; p += 256)
        atomicAdd(&hist[(bins[segs + p].x >> 17) & (CPB - 1)], 1);
    __syncthreads();
    if (tid < CPB) colStart[tid] = hist[tid];
    __syncthreads();
    scan4(colStart, CPB, tid, wtot);
    if (tid == 0) colStart[CPB] = len;
    if (tid < CPB) {
        int cg = b * CPB + tid;
        if (cg < N) start[cg] = segs + colStart[tid];
        cursor[tid] = colStart[tid];
    }
    if (b == (int)gridDim.x - 1 && tid == 0) start[N] = sege;
    __syncthreads();
    int rounds = (len + 255) / 256;
    ull ltm = (lane == 0) ? 0ULL : ((~0ULL) >> (64 - lane));
    for (int r = 0; r < rounds; ++r) {
        int p = r * 256 + tid;
        bool valid = (p < len);
        int2 d = valid ? bins[segs + p] : make_int2(0, 0);
        int c = valid ? ((d.x >> 17) & (CPB - 1)) : 0;
        ull vm = __ballot(valid);
        ull peers = vm;
        for (int bit = 0; bit < 7; ++bit) {
            ull s = __ballot(valid && ((c >> bit) & 1));
            peers &= ((c >> bit) & 1) ? s : ~s;
        }
        int rank = __popcll(peers & ltm);
        int cng  = __popcll(peers);
        int ldr  = __ffsll(peers) - 1;
        if (ldr < 0) ldr = 0;
        int lb = 0;
        for (int w = 0; w < 4; ++w) {
            if (wid == w && valid && rank == 0) lb = atomicAdd(&cursor[c], cng);
            __syncthreads();
        }
        int lbase = __shfl(lb, ldr, 64);
        if (valid) {
            int lpos = lbase + rank;
            if ((unsigned)lpos < (unsigned)CAP) ldata[lpos] = d;
        }
    }
    __syncthreads();
    // coalesced flush — KEEP colL bits (s7 derives col from them)
    for (int p = tid; p < len; p += 256)
        bins[segs + p] = ldata[p];
    if (tid < CPB) {
        int cg = b * CPB + tid;
        if (cg < N) {
            int s0 = colStart[tid], e0 = colStart[tid + 1];
            float dsum = 0.f;
            for (int q = s0; q < e0; ++q)
                dsum = __fadd_rn(dsum, __int_as_float(ldata[q].y));
            dsum = __fadd_rn(dsum, 1.0f);
            dis[cg] = 1.0f / __fsqrt_rn(dsum);   // == 1/np.sqrt
            selfw[cg] = 1.0f / dsum;
        }
    }
}

// ---------------------------------------------------------------------------
// Degree-sorted node permutation (scan-built, no contended global atomics).
// bin = 255 - min(deg,255)  (descending degree).
// ---------------------------------------------------------------------------

__device__ __forceinline__ int deg_bin(const int* start, int i) {
    int d = start[i + 1] - start[i];
    return 255 - (d > 255 ? 255 : d);
}

__global__ __launch_bounds__(256)
void pd1_hist(const int* __restrict__ start, int* __restrict__ HD, int N) {
    __shared__ int hist[256];
    int tid = threadIdx.x;
    hist[tid] = 0;
    __syncthreads();
    int base = blockIdx.x * NPB;
    for (int r = 0; r < NPB / 256; ++r) {
        int i = base + r * 256 + tid;
        if (i < N) atomicAdd(&hist[deg_bin(start, i)], 1);
    }
    __syncthreads();
    HD[blockIdx.x * 256 + tid] = hist[tid];
}

__global__ __launch_bounds__(256)
void pd2a_scan(const int* __restrict__ HD, int* __restrict__ binStart, int nbk) {
    __shared__ int arr[256];
    __shared__ int wtot[4];
    int tid = threadIdx.x;
    int tot = 0;
    for (int k = 0; k < nbk; ++k) tot += HD[k * 256 + tid];
    arr[tid] = tot;
    __syncthreads();
    scan4(arr, 256, tid, wtot);
    binStart[tid] = arr[tid];
}

__global__ __launch_bounds__(256)
void pd2b_off(const int* __restrict__ HD, const int* __restrict__ binStart,
              int* __restrict__ OD, int nbk) {
    int wv = (blockIdx.x * 256 + threadIdx.x) >> 6;
    int lane = threadIdx.x & 63;
    if (wv >= 256) return;
    int run = binStart[wv];
    for (int k0 = 0; k0 < nbk; k0 += 64) {
        int k = k0 + lane;
        int h = (k < nbk) ? HD[k * 256 + wv] : 0;
        int x = h;
        for (int off = 1; off < 64; off <<= 1) {
            int y = __shfl_up(x, off, 64);
            if (lane >= off) x += y;
        }
        if (k < nbk) OD[k * 256 + wv] = run + (x - h);
        run += __shfl(x, 63, 64);
    }
}

__global__ __launch_bounds__(256)
void pd3_fill(const int* __restrict__ start, const int* __restrict__ OD,
              int* __restrict__ perm, int N) {
    __shared__ int cnt[256];
    __shared__ int dlt[256];
    __shared__ int wtot[4];
    int tid = threadIdx.x;
    int lane = tid & 63, wid = tid >> 6;
    int base = blockIdx.x * NPB;
    cnt[tid] = 0;
    __syncthreads();
    for (int r = 0; r < NPB / 256; ++r) {
        int i = base + r * 256 + tid;
        if (i < N) atomicAdd(&cnt[deg_bin(start, i)], 1);
    }
    __syncthreads();
    scan4(cnt, 256, tid, wtot);
    dlt[tid] = OD[blockIdx.x * 256 + tid] - cnt[tid];
    __syncthreads();
    ull ltm = (lane == 0) ? 0ULL : ((~0ULL) >> (64 - lane));
    for (int r = 0; r < NPB / 256; ++r) {
        int i = base + r * 256 + tid;
        bool valid = (i < N);
        int b = valid ? deg_bin(start, i) : 0;
        ull peers = __ballot(valid);
        for (int bit = 0; bit < 8; ++bit) {
            ull s = __ballot(valid && ((b >> bit) & 1));
            peers &= ((b >> bit) & 1) ? s : ~s;
        }
        int rank = __popcll(peers & ltm);
        int cng  = __popcll(peers);
        int ldr  = __ffsll(peers) - 1;
        if (ldr < 0) ldr = 0;
        int lb = 0;
        for (int w = 0; w < 4; ++w) {
            if (wid == w && valid && rank == 0) lb = atomicAdd(&cnt[b], cng);
            __syncthreads();
        }
        int lbase = __shfl(lb, ldr, 64);
        if (valid) {
            int gpos = lbase + rank + dlt[b];
            if ((unsigned)gpos < (unsigned)N) perm[gpos] = i;
        }
    }
}

__global__ void pd4_inv(const int* __restrict__ perm, int* __restrict__ iperm, int N) {
    int j = blockIdx.x * 256 + threadIdx.x;
    if (j < N) {
        int node = perm[j];
        if ((unsigned)node < (unsigned)N) iperm[node] = j;
    }
}

// nodepack[j] = {node, start[node], end[node], selfw[node]}
__global__ void p4_pack(const int* __restrict__ perm, const int* __restrict__ start,
                        const float* __restrict__ selfw, int4* __restrict__ nodepack,
                        int N) {
    int j = blockIdx.x * 256 + threadIdx.x;
    if (j < N) {
        int node = perm[j];
        nodepack[j] = make_int4(node, start[node], start[node + 1],
                                __float_as_int(selfw[node]));
    }
}

// S7: edge-parallel, one block per bucket (coalesced in-place update).
// epack: (row|colL<<17, w) -> (iperm[row], norm). norm = (dis[row]*w)*dis[col].
// Also writes 8 zero pad entries past E (agg4's unguarded chunk prefetch).
__global__ __launch_bounds__(256)
void s7_norm(const int* __restrict__ bStart, int2* __restrict__ epack,
             const float* __restrict__ dis, const int* __restrict__ iperm, int E) {
    int b = blockIdx.x;
    if (b == 0 && threadIdx.x < 8) epack[E + threadIdx.x] = make_int2(0, 0);
    int s = bStart[b], e = bStart[b + 1];
    int cbase = b * CPB;
    for (int p = s + threadIdx.x; p < e; p += 256) {
        int2 d = epack[p];
        int row = d.x & 0x1FFFF;
        int col = cbase + ((d.x >> 17) & (CPB - 1));
        float nm = __fmul_rn(__fmul_rn(dis[row], __int_as_float(d.y)), dis[col]);
        epack[p] = make_int2(iperm[row], __float_as_int(nm));
    }
}

// ---------------------------------------------------------------------------
// Layers in PERMUTED space. Per-scalar FP op order identical to round 2.
// ---------------------------------------------------------------------------

template <int F, bool PERMROW>
__global__ __launch_bounds__(256)
void gemm4(const float* __restrict__ h, const float* __restrict__ W,
           float* __restrict__ hw, const int* __restrict__ perm, int N, int K) {
    int g = blockIdx.x * 256 + threadIdx.x;
    int i = g >> 2, jq = g & 3;
    if (i >= N) return;
    if (jq * 4 >= F) return;
    int row = PERMROW ? perm[i] : i;
    const float4* hv = (const float4*)(h + (long)row * K);
    const float4* Wv = (const float4*)W;
    float4 acc = make_float4(0.f, 0.f, 0.f, 0.f);
    for (int k4 = 0; k4 < K / 4; ++k4) {
        float4 h4 = hv[k4];
        float4 w0 = Wv[(4 * k4 + 0) * (F / 4) + jq];
        acc.x = fmaf(h4.x, w0.x, acc.x); acc.y = fmaf(h4.x, w0.y, acc.y);
        acc.z = fmaf(h4.x, w0.z, acc.z); acc.w = fmaf(h4.x, w0.w, acc.w);
        float4 w1 = Wv[(4 * k4 + 1) * (F / 4) + jq];
        acc.x = fmaf(h4.y, w1.x, acc.x); acc.y = fmaf(h4.y, w1.y, acc.y);
        acc.z = fmaf(h4.y, w1.z, acc.z); acc.w = fmaf(h4.y, w1.w, acc.w);
        float4 w2 = Wv[(4 * k4 + 2) * (F / 4) + jq];
        acc.x = fmaf(h4.z, w2.x, acc.x); acc.y = fmaf(h4.z, w2.y, acc.y);
        acc.z = fmaf(h4.z, w2.z, acc.z); acc.w = fmaf(h4.z, w2.w, acc.w);
        float4 w3 = Wv[(4 * k4 + 3) * (F / 4) + jq];
        acc.x = fmaf(h4.w, w3.x, acc.x); acc.y = fmaf(h4.w, w3.y, acc.y);
        acc.z = fmaf(h4.w, w3.z, acc.z); acc.w = fmaf(h4.w, w3.w, acc.w);
    }
    ((float4*)hw)[(long)i * (F / 4) + jq] = acc;
}

#define FOLD(dd, gg) { float nm = __int_as_float(dd.y); \
    acc.x = __fadd_rn(acc.x, __fmul_rn(nm, gg.x)); \
    acc.y = __fadd_rn(acc.y, __fmul_rn(nm, gg.y)); \
    acc.z = __fadd_rn(acc.z, __fmul_rn(nm, gg.z)); \
    acc.w = __fadd_rn(acc.w, __fmul_rn(nm, gg.w)); }

// agg4: 4-deep software-pipelined in-order fold. epack has 8 zero pad entries
// past E, so chunk prefetches are unguarded (pad row 0 is a safe gather; pad
// values are never folded — fold count is exact).
template <int F, bool FINAL>
__global__ __launch_bounds__(256)
void agg4(const float* __restrict__ hw, const int2* __restrict__ epack,
          const int4* __restrict__ nodepack, const float* __restrict__ bias,
          float* __restrict__ out, int N) {
    int g = blockIdx.x * 256 + threadIdx.x;
    int j = g >> 2, fq = g & 3;
    if (j >= N) return;
    if (fq * 4 >= F) return;
    const float4* hwv = (const float4*)hw;
    int4 np = nodepack[j];
    int s = np.y, e = np.z;
    float sw = __int_as_float(np.w);
    float4 acc = make_float4(0.f, 0.f, 0.f, 0.f);

    int2 d0 = epack[s],     d1 = epack[s + 1],
         d2 = epack[s + 2], d3 = epack[s + 3];
    float4 g0 = hwv[d0.x * (F / 4) + fq], g1 = hwv[d1.x * (F / 4) + fq],
           g2 = hwv[d2.x * (F / 4) + fq], g3 = hwv[d3.x * (F / 4) + fq];
    int p = s;
    int nfull = (e - s) >> 2;
    for (int c = 0; c < nfull; ++c) {
        int pn = p + 4;
        int2 e0 = epack[pn],     e1 = epack[pn + 1],
             e2 = epack[pn + 2], e3 = epack[pn + 3];
        float4 h0 = hwv[e0.x * (F / 4) + fq], h1 = hwv[e1.x * (F / 4) + fq],
               h2 = hwv[e2.x * (F / 4) + fq], h3 = hwv[e3.x * (F / 4) + fq];
        FOLD(d0, g0) FOLD(d1, g1) FOLD(d2, g2) FOLD(d3, g3)
        d0 = e0; d1 = e1; d2 = e2; d3 = e3;
        g0 = h0; g1 = h1; g2 = h2; g3 = h3;
        p = pn;
    }
    int rem = e - p;
    if (rem > 0) FOLD(d0, g0)
    if (rem > 1) FOLD(d1, g1)
    if (rem > 2) FOLD(d2, g2)

    float4 sv = hwv[(long)j * (F / 4) + fq];   // self row: linear in perm space
    acc.x = __fadd_rn(acc.x, __fmul_rn(sw, sv.x));
    acc.y = __fadd_rn(acc.y, __fmul_rn(sw, sv.y));
    acc.z = __fadd_rn(acc.z, __fmul_rn(sw, sv.z));
    acc.w = __fadd_rn(acc.w, __fmul_rn(sw, sv.w));
    float4 bv = ((const float4*)bias)[fq];
    acc.x = fmaxf(__fadd_rn(acc.x, bv.x), 0.f);
    acc.y = fmaxf(__fadd_rn(acc.y, bv.y), 0.f);
    acc.z = fmaxf(__fadd_rn(acc.z, bv.z), 0.f);
    acc.w = fmaxf(__fadd_rn(acc.w, bv.w), 0.f);
    long orow = FINAL ? (long)np.x : (long)j;   // final: scatter to original id
    ((float4*)out)[orow * (F / 4) + fq] = acc;
}

// ---------------------------------------------------------------------------

extern "C" void kernel_launch(void* const* d_in, const int* in_sizes, int n_in,
                              void* d_out, int out_size, void* d_ws, size_t ws_size,
                              hipStream_t stream) {
    const float* x      = (const float*)d_in[0];
    const int*   ei     = (const int*)d_in[1];
    const float* ew     = (const float*)d_in[2];
    const float* W0     = (const float*)d_in[3];
    const float* b0     = (const float*)d_in[4];
    const float* Wmid   = (const float*)d_in[5];
    const float* bmid   = (const float*)d_in[6];
    const float* Wlast  = (const float*)d_in[7];
    const float* blast  = (const float*)d_in[8];

    const int N = in_sizes[0] / DIN;              // 100000
    const int E = in_sizes[2];                    // 3200000
    const int* row32 = ei;
    const int* col32 = ei + E;
    const int nblk = (E + EPB - 1) / EPB;         // 782
    const int NB   = (N + CPB - 1) / CPB;         // 782 (<= NBMAX)
    const int nbk  = (N + NPB - 1) / NPB;         // 98

    char* w = (char*)d_ws;
    size_t off = 0;
    auto alloc = [&](size_t bytes) -> void* {
        void* p = w + off;
        off = (off + bytes + 255) & ~(size_t)255;
        return p;
    };
    int*  T      = (int*)alloc((size_t)NB * 4);
    int*  bStart = (int*)alloc((size_t)(NB + 1) * 4);
    int*  H      = (int*)alloc((size_t)nblk * NB * 4);
    int*  O      = (int*)alloc((size_t)nblk * NB * 4);
    int*  start  = (int*)alloc((size_t)(N + 1) * 4);
    float* dis   = (float*)alloc((size_t)N * 4);
    float* selfw = (float*)alloc((size_t)N * 4);
    int*  HD     = (int*)alloc((size_t)nbk * 256 * 4);
    int*  OD     = (int*)alloc((size_t)nbk * 256 * 4);
    int*  binStart = (int*)alloc(257 * 4);
    int*  perm   = (int*)alloc((size_t)N * 4);
    int*  iperm  = (int*)alloc((size_t)N * 4);
    int4* nodepack = (int4*)alloc((size_t)N * 16);
    int2* bins   = (int2*)alloc(((size_t)E + 8) * 8); // +8 pad for agg prefetch
    float* hbuf  = (float*)alloc((size_t)N * HID * 4);
    float* hwbuf = (float*)alloc((size_t)N * HID * 4);
    (void)ws_size;

    hipMemsetAsync(T, 0, (size_t)NB * 4, stream);

    int gridN1 = (N + 255) / 256;

    s1_hist<<<nblk, 256, 0, stream>>>(col32, H, T, E, N, NB);
    s2b_scan<<<1, 1024, 0, stream>>>(T, bStart, NB);
    s2c_scan<<<(NB * 64 + 255) / 256, 256, 0, stream>>>(H, bStart, O, NB, nblk);
    s3_bin<<<nblk, 256, 0, stream>>>(row32, col32, ew, O, bins, E, N, NB);
    s4_sort<<<NB, 256, 0, stream>>>(bStart, bins, start, dis, selfw, E, N);
    pd1_hist<<<nbk, 256, 0, stream>>>(start, HD, N);
    pd2a_scan<<<1, 256, 0, stream>>>(HD, binStart, nbk);
    pd2b_off<<<64, 256, 0, stream>>>(HD, binStart, OD, nbk);
    pd3_fill<<<nbk, 256, 0, stream>>>(start, OD, perm, N);
    pd4_inv<<<gridN1, 256, 0, stream>>>(perm, iperm, N);
    p4_pack<<<gridN1, 256, 0, stream>>>(perm, start, selfw, nodepack, N);
    s7_norm<<<NB, 256, 0, stream>>>(bStart, bins, dis, iperm, E);
    int2* epack = bins;

    int gridN4 = (N * 4 + 255) / 256;

    gemm4<HID, true><<<gridN4, 256, 0, stream>>>(x, W0, hwbuf, perm, N, DIN);
    agg4<HID, false><<<gridN4, 256, 0, stream>>>(hwbuf, epack, nodepack, b0, hbuf, N);

    for (int l = 0; l < NMID; l++) {
        gemm4<HID, false><<<gridN4, 256, 0, stream>>>(hbuf, Wmid + (size_t)l * HID * HID,
                                                      hwbuf, perm, N, HID);
        agg4<HID, false><<<gridN4, 256, 0, stream>>>(hwbuf, epack, nodepack,
                                                     bmid + (size_t)l * HID, hbuf, N);
    }

    gemm4<DOUT, false><<<gridN4, 256, 0, stream>>>(hbuf, Wlast, hwbuf, perm, N, HID);
    agg4<DOUT, true><<<gridN4, 256, 0, stream>>>(hwbuf, epack, nodepack, blast,
                                                 (float*)d_out, N);
}